// Round 5
// baseline (552.485 us; speedup 1.0000x reference)
//
#include <hip/hip_runtime.h>

#define B_SZ 4096
#define T_SZ 64
#define F_SZ 512
#define H_SZ 64
#define BR 4                   // batch rows per block -> 1024 blocks
#define NTILE 32               // 16KB tiles: 32 mrows x 128 k fp32
#define WIH_ELEMS (256 * 512)

typedef _Float16 f16x8 __attribute__((ext_vector_type(8)));
typedef float f32x4 __attribute__((ext_vector_type(4)));

__device__ __forceinline__ float fast_rcp(float x) { return __builtin_amdgcn_rcpf(x); }
__device__ __forceinline__ float sigm(float x) { return fast_rcp(1.0f + __expf(-x)); }
__device__ __forceinline__ float tanh_f(float x) {
  x = fminf(15.0f, fmaxf(-15.0f, x));
  float e = __expf(2.0f * x);
  return (e - 1.0f) * fast_rcp(e + 1.0f);
}
__device__ __forceinline__ f16x8 cvt8(float4 a, float4 b) {
  f16x8 h;
  h[0] = (_Float16)a.x; h[1] = (_Float16)a.y; h[2] = (_Float16)a.z; h[3] = (_Float16)a.w;
  h[4] = (_Float16)b.x; h[5] = (_Float16)b.y; h[6] = (_Float16)b.z; h[7] = (_Float16)b.w;
  return h;
}
// Untracked loads: compiler's waitcnt pass never sees these -> our asm vmcnt owns them.
__device__ __forceinline__ void gload16(f16x8& d, const _Float16* p) {
  asm volatile("global_load_dwordx4 %0, %1, off" : "=v"(d) : "v"(p) : "memory");
}
__device__ __forceinline__ void gload16o(f16x8& d, const _Float16* p) {
  asm volatile("global_load_dwordx4 %0, %1, off offset:64" : "=v"(d) : "v"(p) : "memory");
}

__global__ void transcode_f16(const float* __restrict__ Wih, const float* __restrict__ Whh,
                              _Float16* __restrict__ ws) {
  const int i4 = (blockIdx.x * 256 + threadIdx.x) * 4;
  if (i4 < WIH_ELEMS) {
    float4 v = *(const float4*)(Wih + i4);
    ws[i4] = (_Float16)v.x; ws[i4+1] = (_Float16)v.y; ws[i4+2] = (_Float16)v.z; ws[i4+3] = (_Float16)v.w;
  } else {
    const int j4 = i4 - WIH_ELEMS;
    float4 v = *(const float4*)(Whh + j4);
    _Float16* w2 = ws + WIH_ELEMS;
    w2[j4] = (_Float16)v.x; w2[j4+1] = (_Float16)v.y; w2[j4+2] = (_Float16)v.z; w2[j4+3] = (_Float16)v.w;
  }
}

// Fused LSTM, hand-counted VMEM stream:
//  - per phase-A iteration exactly: 8 asm B-loads + 2 global_load_lds (1KB, 512B-contig
//    segments), then s_waitcnt vmcnt(12) + sched_barrier(0). Retires B(kk) and the
//    current tile's DMA exactly; 2 tiles + next-B always in flight (incl. phase B).
//  - tile = 32 mrows x 128 k fp32 (16KB); ring of 3; barrier only at tile switch.
//  - both-sides XOR swizzle (source-side for DMA, read-side on ds_read).
//  - BR=4 -> 1024 blocks; ~52KB LDS -> 3 blocks/CU.
__global__ __launch_bounds__(256, 3)
void lstm_fused(const float* __restrict__ x, const _Float16* __restrict__ ws,
                const float* __restrict__ bih, const float* __restrict__ bhh,
                const float* __restrict__ Wfc, const float* __restrict__ bfc,
                float* __restrict__ out)
{
  __shared__ __align__(16) float Ax[3][32 * 128];     // ring: 3 x 16KB
  __shared__ __align__(16) _Float16 hbuf[2][4][72];
  __shared__ float cb[4][64];
  __shared__ float h32[4][64];

  const int tid  = threadIdx.x;
  const int wv   = tid >> 6;
  const int lane = tid & 63;
  const int ln   = lane & 15;
  const int kg   = lane >> 4;
  const int br0  = blockIdx.x * BR;
  const int u    = wv * 16 + ln;
  const int sw   = (ln & 7) << 2;

  const _Float16* Wihh = ws;
  const _Float16* Whhh = ws + WIH_ELEMS;

  for (int i = tid; i < 2 * 4 * 72; i += 256) (&hbuf[0][0][0])[i] = (_Float16)0.0f;
  for (int i = tid; i < 4 * 64; i += 256) (&cb[0][0])[i] = 0.0f;

  // Whh fragments: plain loads, pinned to prologue via keep-alive asm.
  f16x8 whhf[4][2];
  #pragma unroll
  for (int g = 0; g < 4; ++g)
    #pragma unroll
    for (int k2 = 0; k2 < 2; ++k2) {
      whhf[g][k2] = *(const f16x8*)(Whhh + (size_t)((g * 4 + wv) * 16 + ln) * H_SZ
                                         + kg * 8 + k2 * 32);
      asm volatile("" :: "v"(whhf[g][k2]));
    }
  float bsum[4];
  #pragma unroll
  for (int g = 0; g < 4; ++g) bsum[g] = bih[g * 64 + u] + bhh[g * 64 + u];

  __syncthreads();   // zeros visible; full drain BEFORE any untracked VMEM

  // DMA half-issue: tile q, half h -> 2 instrs/wave (1KB each, two 512B segments)
  auto issueD = [&](int q, int h) {
    const int qa   = q < NTILE ? q : NTILE - 1;   // tail dummies keep the count uniform
    const int cc   = qa >> 2, kq = qa & 3;
    const int slot = q % 3;
    #pragma unroll
    for (int j = 0; j < 2; ++j) {
      const int i    = wv * 4 + h * 2 + j;
      const int mrow = 2 * i + (lane >> 5);
      const int w    = (lane & 31) * 4;
      const float* gp = x + (size_t)(br0 + (mrow & 3)) * (T_SZ * F_SZ)
                          + (size_t)(cc * 8 + (mrow >> 2)) * F_SZ
                          + kq * 128 + (w ^ ((mrow & 7) << 2));
      __builtin_amdgcn_global_load_lds(gp, &Ax[slot][i * 256], 16, 0, 0);
    }
  };
  auto loadB = [&](f16x8 (&b)[4][2], int kk) {
    #pragma unroll
    for (int g = 0; g < 4; ++g) {
      const _Float16* p0 = Wihh + (size_t)((g * 4 + wv) * 16 + ln) * F_SZ + kk * 64 + kg * 8;
      gload16(b[g][0], p0);
      gload16o(b[g][1], p0);   // +32 elems
    }
  };

  f32x4 acc[2][4];
  f16x8 bA[4][2], bB[4][2];

  // One phase-A iteration (consumes bcur=B(kk), prefetches bnext=B(kk+1)).
  auto iterA = [&](int cc, int kk, f16x8 (&bcur)[4][2], f16x8 (&bnext)[4][2]) {
    const int it = cc * 8 + kk;
    const int q  = it >> 1;
    loadB(bnext, (kk + 1) & 7);
    issueD(q + 2, it & 1);
    __builtin_amdgcn_sched_barrier(0);
    asm volatile("s_waitcnt vmcnt(12)" ::: "memory");   // retires B(kk) + tile q's DMA
    __builtin_amdgcn_sched_barrier(0);
    const float* axs = &Ax[q % 3][0];
    const int sub = (kk & 1) * 64;
    #pragma unroll
    for (int t = 0; t < 2; ++t) {
      const int rb = (t * 16 + ln) * 128;
      const int w0 = (kg * 8) ^ sw;
      float4 a0 = *(const float4*)(axs + rb + sub + w0);
      float4 a1 = *(const float4*)(axs + rb + sub + (w0 ^ 4));
      float4 a2 = *(const float4*)(axs + rb + sub + 32 + w0);
      float4 a3 = *(const float4*)(axs + rb + sub + 32 + (w0 ^ 4));
      f16x8 af0 = cvt8(a0, a1);
      f16x8 af1 = cvt8(a2, a3);
      #pragma unroll
      for (int g = 0; g < 4; ++g) {
        acc[t][g] = __builtin_amdgcn_mfma_f32_16x16x32_f16(af0, bcur[g][0], acc[t][g], 0, 0, 0);
        acc[t][g] = __builtin_amdgcn_mfma_f32_16x16x32_f16(af1, bcur[g][1], acc[t][g], 0, 0, 0);
      }
    }
  };

  // Prologue shaped to the steady-state invariant: D0:4, D1h0:2, B0:8, D1h1:2,
  // then vmcnt(12) retires exactly D0.
  issueD(0, 0); issueD(0, 1);
  issueD(1, 0);
  loadB(bA, 0);
  issueD(1, 1);
  __builtin_amdgcn_sched_barrier(0);
  asm volatile("s_waitcnt vmcnt(12)" ::: "memory");
  __builtin_amdgcn_s_barrier();

  for (int cc = 0; cc < 8; ++cc) {
    #pragma unroll
    for (int t = 0; t < 2; ++t)
      #pragma unroll
      for (int g = 0; g < 4; ++g) acc[t][g] = (f32x4){0.0f, 0.0f, 0.0f, 0.0f};

    // ---- Phase A: 8 iterations, tile switch every 2; barrier only at switch ----
    #pragma unroll
    for (int kp = 0; kp < 4; ++kp) {
      if (kp) __builtin_amdgcn_s_barrier();   // kk=0's barrier = prologue / phase-B tail
      iterA(cc, 2 * kp,     bA, bB);
      iterA(cc, 2 * kp + 1, bB, bA);
    }

    // ---- Phase B: 8 sequential steps; step s -> M-tile s>>2, lane-quarter s&3 ----
    #pragma unroll
    for (int s = 0; s < 8; ++s) {
      const int st = cc * 8 + s;
      const int t  = s >> 2, kq = s & 3;
      f16x8 ah0 = (f16x8){0, 0, 0, 0, 0, 0, 0, 0};
      f16x8 ah1 = (f16x8){0, 0, 0, 0, 0, 0, 0, 0};
      if ((ln >> 2) == kq) {                   // A rows (s&3)*4 + r carry h
        const _Float16* hr = &hbuf[st & 1][ln & 3][0];
        ah0 = *(const f16x8*)(hr + kg * 8);
        ah1 = *(const f16x8*)(hr + kg * 8 + 32);
      }
      #pragma unroll
      for (int g = 0; g < 4; ++g) {            // accumulate into own quarter only
        acc[t][g] = __builtin_amdgcn_mfma_f32_16x16x32_f16(ah0, whhf[g][0], acc[t][g], 0, 0, 0);
        acc[t][g] = __builtin_amdgcn_mfma_f32_16x16x32_f16(ah1, whhf[g][1], acc[t][g], 0, 0, 0);
      }
      if (kg == kq) {                          // C rows kg*4+r -> step s, row r
        #pragma unroll
        for (int r = 0; r < 4; ++r) {
          const float iv = sigm(acc[t][0][r] + bsum[0]);
          const float fv = sigm(acc[t][1][r] + bsum[1]);
          const float gv = tanh_f(acc[t][2][r] + bsum[2]);
          const float ov = sigm(acc[t][3][r] + bsum[3]);
          const float cn = fv * cb[r][u] + iv * gv;
          cb[r][u] = cn;
          const float hn = ov * tanh_f(cn);
          hbuf[(st + 1) & 1][r][u] = (_Float16)hn;
          if (st == T_SZ - 1) h32[r][u] = hn;
        }
      }
      asm volatile("s_waitcnt lgkmcnt(0)" ::: "memory");
      __builtin_amdgcn_s_barrier();            // raw: DMA stays in flight
      __builtin_amdgcn_sched_barrier(0);       // pin next step's h-reads below barrier
    }
  }

  __syncthreads();   // epilogue: full drain OK
  if (tid < 8) {
    const int r = tid >> 1, j = tid & 1;
    float a = bfc[j];
    #pragma unroll
    for (int uu = 0; uu < 64; ++uu) a += h32[r][uu] * Wfc[j * 64 + uu];
    out[(size_t)(br0 + r) * 2 + j] = a;
  }
}

extern "C" void kernel_launch(void* const* d_in, const int* in_sizes, int n_in,
                              void* d_out, int out_size, void* d_ws, size_t ws_size,
                              hipStream_t stream) {
  const float* x   = (const float*)d_in[0];
  const float* Wih = (const float*)d_in[1];
  const float* Whh = (const float*)d_in[2];
  const float* bih = (const float*)d_in[3];
  const float* bhh = (const float*)d_in[4];
  const float* Wfc = (const float*)d_in[5];
  const float* bfc = (const float*)d_in[6];
  float* out = (float*)d_out;
  _Float16* ws = (_Float16*)d_ws;   // 288KB used

  transcode_f16<<<dim3(144), dim3(256), 0, stream>>>(Wih, Whh, ws);
  lstm_fused<<<dim3(B_SZ / BR), dim3(256), 0, stream>>>(x, ws, bih, bhh, Wfc, bfc, out);
}

// Round 6
// 379.438 us; speedup vs baseline: 1.4561x; 1.4561x over previous
//
#include <hip/hip_runtime.h>

#define B_SZ 4096
#define T_SZ 64
#define F_SZ 512
#define H_SZ 64
#define BR 4                   // 1024 blocks = 4 blocks/CU x 256 CUs, zero tail
#define WIH_ELEMS (256 * 512)

typedef _Float16 f16x8 __attribute__((ext_vector_type(8)));
typedef float f32x4 __attribute__((ext_vector_type(4)));

__device__ __forceinline__ float fast_rcp(float x) { return __builtin_amdgcn_rcpf(x); }
__device__ __forceinline__ float sigm(float x) { return fast_rcp(1.0f + __expf(-x)); }
__device__ __forceinline__ float tanh_f(float x) {
  x = fminf(15.0f, fmaxf(-15.0f, x));
  float e = __expf(2.0f * x);
  return (e - 1.0f) * fast_rcp(e + 1.0f);
}
__device__ __forceinline__ f16x8 cvt8(float4 a, float4 b) {
  f16x8 h;
  h[0] = (_Float16)a.x; h[1] = (_Float16)a.y; h[2] = (_Float16)a.z; h[3] = (_Float16)a.w;
  h[4] = (_Float16)b.x; h[5] = (_Float16)b.y; h[6] = (_Float16)b.z; h[7] = (_Float16)b.w;
  return h;
}

__global__ void transcode_f16(const float* __restrict__ Wih, const float* __restrict__ Whh,
                              _Float16* __restrict__ ws) {
  const int i4 = (blockIdx.x * 256 + threadIdx.x) * 4;
  if (i4 < WIH_ELEMS) {
    float4 v = *(const float4*)(Wih + i4);
    ws[i4] = (_Float16)v.x; ws[i4+1] = (_Float16)v.y; ws[i4+2] = (_Float16)v.z; ws[i4+3] = (_Float16)v.w;
  } else {
    const int j4 = i4 - WIH_ELEMS;
    float4 v = *(const float4*)(Whh + j4);
    _Float16* w2 = ws + WIH_ELEMS;
    w2[j4] = (_Float16)v.x; w2[j4+1] = (_Float16)v.y; w2[j4+2] = (_Float16)v.z; w2[j4+3] = (_Float16)v.w;
  }
}

// Fused LSTM, ALL VMEM compiler-tracked (no asm loads, no global_load_lds, no manual vmcnt).
// Per 64-K panel: {load B-frags, load next x->regs} -> MFMA (waits vmcnt(2): x stays in
// flight) -> ONE raw barrier per panel -> cvt+ds_write next panel. Issue order makes every
// compiler wait counted; x loads are in flight across the whole MFMA phase and (via the
// P+2 prefetch distance) across phase B too. fp16 LDS panels (4KB), XOR-swizzled granules.
__global__ __launch_bounds__(256, 4)
void lstm_fused(const float* __restrict__ x, const _Float16* __restrict__ ws,
                const float* __restrict__ bih, const float* __restrict__ bhh,
                const float* __restrict__ Wfc, const float* __restrict__ bfc,
                float* __restrict__ out)
{
  __shared__ __align__(16) _Float16 Abuf[2][32 * 64];   // panel: 32 mrows x 64 k fp16
  __shared__ __align__(16) _Float16 hbuf[2][4][72];
  __shared__ float cb[4][64];
  __shared__ float h32[4][64];

  const int tid  = threadIdx.x;
  const int wv   = tid >> 6;
  const int lane = tid & 63;
  const int ln   = lane & 15;
  const int kg   = lane >> 4;
  const int br0  = blockIdx.x * BR;
  const int u    = wv * 16 + ln;

  const _Float16* Wihh = ws;
  const _Float16* Whhh = ws + WIH_ELEMS;

  for (int i = tid; i < 2 * 4 * 72; i += 256) (&hbuf[0][0][0])[i] = (_Float16)0.0f;
  for (int i = tid; i < 4 * 64; i += 256) (&cb[0][0])[i] = 0.0f;

  float bsum[4];
  #pragma unroll
  for (int g = 0; g < 4; ++g) bsum[g] = bih[g * 64 + u] + bhh[g * 64 + u];
  __syncthreads();

  // x staging: thread -> (mrow = s*4+r, kblk); 8 floats per thread per panel.
  const int mrow = tid >> 3;            // 0..31
  const int kblk = tid & 7;
  const float* xbase = x + (size_t)(br0 + (mrow & 3)) * (T_SZ * F_SZ)
                         + (size_t)(mrow >> 2) * F_SZ + kblk * 8;
  auto xaddr = [&](int P) {
    const int Pc = P < 63 ? P : 63;     // tail clamp: L2-hit re-reads, data never consumed
    return xbase + (size_t)(Pc >> 3) * (8 * F_SZ) + (Pc & 7) * 64;
  };
  const int wgr = kblk ^ (mrow & 7);    // XOR-swizzled physical granule
  _Float16* const wdst0 = &Abuf[0][mrow * 64 + wgr * 8];
  _Float16* const wdst1 = &Abuf[1][mrow * 64 + wgr * 8];

  f16x8 whhf[4][2];
  f32x4 acc[2][4];

// One panel: P = panel index (BUFIDX = P&1 literal). Consumes S0,S1 = x(P+1) into
// buf[BUFIDX^1]; issues x(P+2) into D0,D1. LAST(=panel 7): load whhf after MFMA.
#define PANEL(Pexp, BUFIDX, S0, S1, D0, D1, LAST)                                        \
  do {                                                                                   \
    const int P_ = (Pexp);                                                               \
    f16x8 bfr[4][2];                                                                     \
    _Pragma("unroll")                                                                    \
    for (int g = 0; g < 4; ++g) {                                                        \
      const _Float16* wp = Wihh + (size_t)(g * 64 + u) * F_SZ + (P_ & 7) * 64 + kg * 8;  \
      bfr[g][0] = *(const f16x8*)wp;                                                     \
      bfr[g][1] = *(const f16x8*)(wp + 32);                                              \
    }                                                                                    \
    { const float* xa = xaddr(P_ + 2);                                                   \
      D0 = ((const float4*)xa)[0]; D1 = ((const float4*)xa)[1]; }                        \
    __builtin_amdgcn_sched_barrier(0);                                                   \
    { const _Float16* ab = &Abuf[BUFIDX][0];                                             \
      _Pragma("unroll")                                                                  \
      for (int t = 0; t < 2; ++t) {                                                      \
        const int m  = t * 16 + ln;                                                      \
        const _Float16* rp = ab + m * 64;                                                \
        f16x8 af0 = *(const f16x8*)(rp + ((kg ^ (m & 7)) * 8));                          \
        f16x8 af1 = *(const f16x8*)(rp + (((kg + 4) ^ (m & 7)) * 8));                    \
        _Pragma("unroll")                                                                \
        for (int g = 0; g < 4; ++g) {                                                    \
          acc[t][g] = __builtin_amdgcn_mfma_f32_16x16x32_f16(af0, bfr[g][0], acc[t][g], 0, 0, 0); \
          acc[t][g] = __builtin_amdgcn_mfma_f32_16x16x32_f16(af1, bfr[g][1], acc[t][g], 0, 0, 0); \
        }                                                                                \
      }                                                                                  \
    }                                                                                    \
    if (LAST) {   /* bfr dead here -> whhf reuses its registers */                       \
      _Pragma("unroll")                                                                  \
      for (int g = 0; g < 4; ++g) {                                                      \
        const _Float16* wp = Whhh + (size_t)(g * 64 + u) * H_SZ + kg * 8;                \
        whhf[g][0] = *(const f16x8*)wp;                                                  \
        whhf[g][1] = *(const f16x8*)(wp + 32);                                           \
      }                                                                                  \
    }                                                                                    \
    *(f16x8*)((BUFIDX) ? wdst0 : wdst1) = cvt8(S0, S1);                                  \
    asm volatile("s_waitcnt lgkmcnt(0)" ::: "memory");                                   \
    __builtin_amdgcn_s_barrier();                                                        \
    asm volatile("" ::: "memory");                                                       \
  } while (0)

  // Prologue: x(0)->rA, x(1)->rB, write panel 0.
  float4 rA0, rA1, rB0, rB1;
  { const float* xa = xaddr(0); rA0 = ((const float4*)xa)[0]; rA1 = ((const float4*)xa)[1]; }
  { const float* xa = xaddr(1); rB0 = ((const float4*)xa)[0]; rB1 = ((const float4*)xa)[1]; }
  *(f16x8*)wdst0 = cvt8(rA0, rA1);
  asm volatile("s_waitcnt lgkmcnt(0)" ::: "memory");
  __builtin_amdgcn_s_barrier();
  asm volatile("" ::: "memory");

  for (int cc = 0; cc < 8; ++cc) {
    #pragma unroll
    for (int t = 0; t < 2; ++t)
      #pragma unroll
      for (int g = 0; g < 4; ++g) acc[t][g] = (f32x4){0.0f, 0.0f, 0.0f, 0.0f};

    // ---- Phase A: 8 panels (K=512), one raw barrier each ----
    #pragma unroll
    for (int pp = 0; pp < 4; ++pp) {
      PANEL(cc * 8 + 2 * pp,     0, rB0, rB1, rA0, rA1, false);
      PANEL(cc * 8 + 2 * pp + 1, 1, rA0, rA1, rB0, rB1, (pp == 3));
    }

    // ---- Phase B: 8 sequential steps; step s -> M-tile s>>2, lane-quarter s&3 ----
    #pragma unroll
    for (int s = 0; s < 8; ++s) {
      const int st = cc * 8 + s;
      const int t  = s >> 2, kq = s & 3;
      f16x8 ah0 = (f16x8){0, 0, 0, 0, 0, 0, 0, 0};
      f16x8 ah1 = (f16x8){0, 0, 0, 0, 0, 0, 0, 0};
      if ((ln >> 2) == kq) {
        const _Float16* hr = &hbuf[s & 1][ln & 3][0];
        ah0 = *(const f16x8*)(hr + kg * 8);
        ah1 = *(const f16x8*)(hr + kg * 8 + 32);
      }
      #pragma unroll
      for (int g = 0; g < 4; ++g) {
        acc[t][g] = __builtin_amdgcn_mfma_f32_16x16x32_f16(ah0, whhf[g][0], acc[t][g], 0, 0, 0);
        acc[t][g] = __builtin_amdgcn_mfma_f32_16x16x32_f16(ah1, whhf[g][1], acc[t][g], 0, 0, 0);
      }
      if (kg == kq) {
        #pragma unroll
        for (int r = 0; r < 4; ++r) {
          const float iv = sigm(acc[t][0][r] + bsum[0]);
          const float fv = sigm(acc[t][1][r] + bsum[1]);
          const float gv = tanh_f(acc[t][2][r] + bsum[2]);
          const float ov = sigm(acc[t][3][r] + bsum[3]);
          const float cn = fv * cb[r][u] + iv * gv;
          cb[r][u] = cn;
          const float hn = ov * tanh_f(cn);
          hbuf[(s + 1) & 1][r][u] = (_Float16)hn;
          if (st == T_SZ - 1) h32[r][u] = hn;
        }
      }
      asm volatile("s_waitcnt lgkmcnt(0)" ::: "memory");
      __builtin_amdgcn_s_barrier();
      asm volatile("" ::: "memory");
      __builtin_amdgcn_sched_barrier(0);
    }
  }

  __syncthreads();
  if (tid < 8) {
    const int r = tid >> 1, j = tid & 1;
    float a = bfc[j];
    #pragma unroll
    for (int uu = 0; uu < 64; ++uu) a += h32[r][uu] * Wfc[j * 64 + uu];
    out[(size_t)(br0 + r) * 2 + j] = a;
  }
#undef PANEL
}

extern "C" void kernel_launch(void* const* d_in, const int* in_sizes, int n_in,
                              void* d_out, int out_size, void* d_ws, size_t ws_size,
                              hipStream_t stream) {
  const float* x   = (const float*)d_in[0];
  const float* Wih = (const float*)d_in[1];
  const float* Whh = (const float*)d_in[2];
  const float* bih = (const float*)d_in[3];
  const float* bhh = (const float*)d_in[4];
  const float* Wfc = (const float*)d_in[5];
  const float* bfc = (const float*)d_in[6];
  float* out = (float*)d_out;
  _Float16* ws = (_Float16*)d_ws;   // 288KB used

  transcode_f16<<<dim3(144), dim3(256), 0, stream>>>(Wih, Whh, ws);
  lstm_fused<<<dim3(B_SZ / BR), dim3(256), 0, stream>>>(x, ws, bih, bhh, Wfc, bfc, out);
}

// Round 7
// 341.453 us; speedup vs baseline: 1.6180x; 1.1112x over previous
//
#include <hip/hip_runtime.h>

#define B_SZ 4096
#define T_SZ 64
#define F_SZ 512
#define H_SZ 64
#define WIH_ELEMS (256 * 512)
#define WHH_ELEMS (256 * 64)
#define XG_ELEMS ((size_t)B_SZ * T_SZ * 256)

typedef _Float16 f16x4 __attribute__((ext_vector_type(4)));
typedef _Float16 f16x8 __attribute__((ext_vector_type(8)));
typedef float f32x4 __attribute__((ext_vector_type(4)));

__device__ __forceinline__ float fast_rcp(float x) { return __builtin_amdgcn_rcpf(x); }
__device__ __forceinline__ float sigm(float x) { return fast_rcp(1.0f + __expf(-x)); }
__device__ __forceinline__ float tanh_f(float x) {
  x = fminf(15.0f, fmaxf(-15.0f, x));
  float e = __expf(2.0f * x);
  return (e - 1.0f) * fast_rcp(e + 1.0f);
}
__device__ __forceinline__ f16x8 cvt8(float4 a, float4 b) {
  f16x8 h;
  h[0] = (_Float16)a.x; h[1] = (_Float16)a.y; h[2] = (_Float16)a.z; h[3] = (_Float16)a.w;
  h[4] = (_Float16)b.x; h[5] = (_Float16)b.y; h[6] = (_Float16)b.z; h[7] = (_Float16)b.w;
  return h;
}

__global__ void transcode_f16(const float* __restrict__ Wih, const float* __restrict__ Whh,
                              _Float16* __restrict__ ws) {
  const int i4 = (blockIdx.x * 256 + threadIdx.x) * 4;
  if (i4 < WIH_ELEMS) {
    float4 v = *(const float4*)(Wih + i4);
    ws[i4] = (_Float16)v.x; ws[i4+1] = (_Float16)v.y; ws[i4+2] = (_Float16)v.z; ws[i4+3] = (_Float16)v.w;
  } else {
    const int j4 = i4 - WIH_ELEMS;
    float4 v = *(const float4*)(Whh + j4);
    _Float16* w2 = ws + WIH_ELEMS;
    w2[j4] = (_Float16)v.x; w2[j4+1] = (_Float16)v.y; w2[j4+2] = (_Float16)v.z; w2[j4+3] = (_Float16)v.w;
  }
}

// ---------------- K1: xg[t][b][n'] = x[b,t,:] @ Wih^T + (bih+bhh), fp16 ----------------
// Block = one batch row b: 64 t-rows x 512 k. Stage (1KB/instr coalesced) -> LDS fp16,
// one barrier, 16 K-steps MFMA (B-frags direct from L2-hot fp16 Wih), bounce epilogue,
// 512B-contiguous stores. n' = u*4 + g (gate-interleaved for the scan kernel).
__global__ __launch_bounds__(256, 2)
void xg_gemm(const float* __restrict__ x, const _Float16* __restrict__ ws,
             const float* __restrict__ bih, const float* __restrict__ bhh,
             _Float16* __restrict__ xg)
{
  __shared__ __align__(16) _Float16 A[64][520];   // 66.6 KB; epilogue bounce reuses

  const int tid = threadIdx.x, wv = tid >> 6, lane = tid & 63;
  const int ln = lane & 15, kg = lane >> 4;
  const int b = blockIdx.x;
  const int u = wv * 16 + ln;
  const _Float16* Wihh = ws;

  // stage: wave wv covers t-rows [wv*16, wv*16+16); each instr = 64 lanes x 16B = 1KB contig
  {
    const float* src = x + (size_t)b * (T_SZ * F_SZ) + wv * 8192;
    #pragma unroll 4
    for (int i = 0; i < 32; ++i) {
      float4 v = ((const float4*)src)[i * 64 + lane];
      f16x4 h = {(_Float16)v.x, (_Float16)v.y, (_Float16)v.z, (_Float16)v.w};
      const int m = wv * 16 + (i >> 1);
      const int k = (i & 1) * 256 + lane * 4;
      *(f16x4*)&A[m][k] = h;
    }
  }
  float bb[4];
  #pragma unroll
  for (int g = 0; g < 4; ++g) bb[g] = bih[g * 64 + u] + bhh[g * 64 + u];
  __syncthreads();

  f32x4 acc[4][4];
  #pragma unroll
  for (int mt = 0; mt < 4; ++mt)
    #pragma unroll
    for (int g = 0; g < 4; ++g) acc[mt][g] = (f32x4){bb[g], bb[g], bb[g], bb[g]};

  #pragma unroll 2
  for (int kk = 0; kk < 16; ++kk) {
    f16x8 bfr[4];
    #pragma unroll
    for (int g = 0; g < 4; ++g)
      bfr[g] = *(const f16x8*)(Wihh + (size_t)((g * 4 + wv) * 16 + ln) * F_SZ + kk * 32 + kg * 8);
    #pragma unroll
    for (int mt = 0; mt < 4; ++mt) {
      f16x8 af = *(const f16x8*)&A[mt * 16 + ln][kk * 32 + kg * 8];
      #pragma unroll
      for (int g = 0; g < 4; ++g)
        acc[mt][g] = __builtin_amdgcn_mfma_f32_16x16x32_f16(af, bfr[g], acc[mt][g], 0, 0, 0);
    }
  }

  __syncthreads();                      // all A reads done -> reuse as bounce [64][264]
  _Float16* bn = &A[0][0];
  #pragma unroll
  for (int mt = 0; mt < 4; ++mt)
    #pragma unroll
    for (int r = 0; r < 4; ++r) {
      f16x4 p = {(_Float16)acc[mt][0][r], (_Float16)acc[mt][1][r],
                 (_Float16)acc[mt][2][r], (_Float16)acc[mt][3][r]};
      *(f16x4*)(bn + (size_t)(mt * 16 + kg * 4 + r) * 264 + u * 4) = p;
    }
  __syncthreads();
  {
    const int t = tid >> 2, seg = tid & 3;
    _Float16* dst = xg + ((size_t)t * B_SZ + b) * 256 + seg * 64;
    const _Float16* srcb = bn + (size_t)t * 264 + seg * 64;
    #pragma unroll
    for (int j = 0; j < 8; ++j)
      *(f16x8*)(dst + j * 8) = *(const f16x8*)(srcb + j * 8);
  }
}

// ---------------- K2: LSTM scan over precomputed xg ----------------
// 512 blocks x 256 thr; block owns 8 batch rows, all 64 steps. Chunk = 4 steps staged in
// LDS (dbuf), chunk c+1 register-prefetched across chunk c's compute. c-state in regs
// (kg<2 lanes), h through LDS. Bias already folded into xg by K1.
__global__ __launch_bounds__(256, 2)
void lstm_scan(const _Float16* __restrict__ xg, const _Float16* __restrict__ ws,
               const float* __restrict__ Wfc, const float* __restrict__ bfc,
               float* __restrict__ out)
{
  __shared__ __align__(16) _Float16 Xs[2][4][8][264];   // 33.8 KB
  __shared__ __align__(16) _Float16 hbuf[2][8][72];
  __shared__ float h32[8][64];

  const int tid = threadIdx.x, wv = tid >> 6, lane = tid & 63;
  const int ln = lane & 15, kg = lane >> 4;
  const int br0 = blockIdx.x * 8;
  const int u = wv * 16 + ln;
  const _Float16* Whhh = ws + WIH_ELEMS;

  for (int i = tid; i < 2 * 8 * 72; i += 256) (&hbuf[0][0][0])[i] = (_Float16)0.0f;

  f16x8 whhf[4][2];
  #pragma unroll
  for (int g = 0; g < 4; ++g)
    #pragma unroll
    for (int k2 = 0; k2 < 2; ++k2)
      whhf[g][k2] = *(const f16x8*)(Whhh + (size_t)((g * 4 + wv) * 16 + ln) * H_SZ
                                         + kg * 8 + k2 * 32);

  f32x4 cst = {0.0f, 0.0f, 0.0f, 0.0f};

  // prefetch chunk 0 (wave wv = step-slot wv; each instr = 1KB contiguous)
  uint4 pf[4];
  {
    const _Float16* gsrc = xg + ((size_t)(0 * 4 + wv) * B_SZ + br0) * 256;
    #pragma unroll
    for (int i = 0; i < 4; ++i) pf[i] = *(const uint4*)(gsrc + (i * 64 + lane) * 8);
  }
  __syncthreads();   // hbuf zeros visible

  for (int c = 0; c < 16; ++c) {
    // write chunk c to LDS
    #pragma unroll
    for (int i = 0; i < 4; ++i)
      *(uint4*)&Xs[c & 1][wv][i * 2 + (lane >> 5)][(lane & 31) * 8] = pf[i];
    // prefetch chunk c+1 (in flight across this chunk's 4 steps)
    {
      const int cn = c < 15 ? c + 1 : 15;
      const _Float16* gsrc = xg + ((size_t)(cn * 4 + wv) * B_SZ + br0) * 256;
      #pragma unroll
      for (int i = 0; i < 4; ++i) pf[i] = *(const uint4*)(gsrc + (i * 64 + lane) * 8);
    }
    __syncthreads();   // Xs writes visible

    #pragma unroll
    for (int sl = 0; sl < 4; ++sl) {
      const int st = c * 4 + sl;
      const _Float16* hr = &hbuf[st & 1][ln & 7][0];   // rows >=8 garbage: row-separable, unused
      f16x8 ah0 = *(const f16x8*)(hr + kg * 8);
      f16x8 ah1 = *(const f16x8*)(hr + kg * 8 + 32);
      f32x4 gf[4];
      if (kg < 2) {
        f16x4 xv[4];
        #pragma unroll
        for (int r = 0; r < 4; ++r)
          xv[r] = *(const f16x4*)&Xs[c & 1][sl][kg * 4 + r][u * 4];
        #pragma unroll
        for (int g = 0; g < 4; ++g)
          gf[g] = (f32x4){(float)xv[0][g], (float)xv[1][g], (float)xv[2][g], (float)xv[3][g]};
      } else {
        #pragma unroll
        for (int g = 0; g < 4; ++g) gf[g] = (f32x4){0.0f, 0.0f, 0.0f, 0.0f};
      }
      #pragma unroll
      for (int g = 0; g < 4; ++g) {
        gf[g] = __builtin_amdgcn_mfma_f32_16x16x32_f16(ah0, whhf[g][0], gf[g], 0, 0, 0);
        gf[g] = __builtin_amdgcn_mfma_f32_16x16x32_f16(ah1, whhf[g][1], gf[g], 0, 0, 0);
      }
      if (kg < 2) {
        #pragma unroll
        for (int r = 0; r < 4; ++r) {
          const float iv = sigm(gf[0][r]);
          const float fv = sigm(gf[1][r]);
          const float gv = tanh_f(gf[2][r]);
          const float ov = sigm(gf[3][r]);
          const float cn = fv * cst[r] + iv * gv;
          cst[r] = cn;
          const float hn = ov * tanh_f(cn);
          hbuf[(st + 1) & 1][kg * 4 + r][u] = (_Float16)hn;
          if (st == T_SZ - 1) h32[kg * 4 + r][u] = hn;
        }
      }
      __syncthreads();
    }
  }

  if (tid < 16) {
    const int r = tid >> 1, j = tid & 1;
    float a = bfc[j];
    #pragma unroll
    for (int uu = 0; uu < 64; ++uu) a += h32[r][uu] * Wfc[j * 64 + uu];
    out[(size_t)(br0 + r) * 2 + j] = a;
  }
}

// ---------------- Fallback: R4 fused kernel (used only if ws too small for xg) ----------------
__global__ __launch_bounds__(256, 2)
void lstm_fused_fb(const float* __restrict__ x, const _Float16* __restrict__ ws,
                   const float* __restrict__ bih, const float* __restrict__ bhh,
                   const float* __restrict__ Wfc, const float* __restrict__ bfc,
                   float* __restrict__ out)
{
  __shared__ __align__(16) float Ax[4][64 * 64];
  __shared__ __align__(16) _Float16 hbuf[2][8][72];
  __shared__ float cb[8][64];
  __shared__ float h32[8][64];

  const int tid  = threadIdx.x;
  const int wv   = tid >> 6;
  const int lane = tid & 63;
  const int ln   = lane & 15;
  const int kg   = lane >> 4;
  const int br0  = blockIdx.x * 8;
  const int u    = wv * 16 + ln;

  const _Float16* Wihh = ws;
  const _Float16* Whhh = ws + WIH_ELEMS;

  for (int i = tid; i < 8 * 72; i += 256) (&hbuf[0][0][0])[i] = (_Float16)0.0f;
  for (int i = tid; i < 8 * 64; i += 256) (&cb[0][0])[i] = 0.0f;
  __syncthreads();

  f16x8 whhf[4][2];
  #pragma unroll
  for (int g = 0; g < 4; ++g)
    #pragma unroll
    for (int k2 = 0; k2 < 2; ++k2)
      whhf[g][k2] = *(const f16x8*)(Whhh + (size_t)((g * 4 + wv) * 16 + ln) * H_SZ
                                         + kg * 8 + k2 * 32);

  float bsum[4];
  #pragma unroll
  for (int g = 0; g < 4; ++g) bsum[g] = bih[g * 64 + u] + bhh[g * 64 + u];

  auto issue_tile = [&](int tau) {
    if (tau >= 64) return;
    const int cc = tau >> 3, kk = tau & 7, slot = tau & 3;
    #pragma unroll
    for (int j = 0; j < 4; ++j) {
      const int i = wv * 4 + j;
      const int m = i * 4 + (lane >> 4);
      const int kw = (((lane & 15) << 2) ^ ((m & 7) << 2));
      const float* gp = x + (size_t)(br0 + (m & 7)) * (T_SZ * F_SZ)
                          + (size_t)(cc * 8 + (m >> 3)) * F_SZ + kk * 64 + kw;
      __builtin_amdgcn_global_load_lds(gp, &Ax[slot][i * 256], 16, 0, 0);
    }
  };
  auto load_bfr = [&](f16x8 (&bf)[4][2], int kk) {
    #pragma unroll
    for (int g = 0; g < 4; ++g)
      #pragma unroll
      for (int k2 = 0; k2 < 2; ++k2)
        bf[g][k2] = *(const f16x8*)(Wihh + (size_t)((g * 4 + wv) * 16 + ln) * F_SZ
                                         + kk * 64 + kg * 8 + k2 * 32);
  };

  f32x4 acc[4][4];
  const int sw = (ln & 7) << 2;

  auto phaseA_iter = [&](int tau, f16x8 (&bcon)[4][2], f16x8 (&bpre)[4][2]) {
    asm volatile("s_waitcnt vmcnt(16)" ::: "memory");
    __builtin_amdgcn_s_barrier();
    load_bfr(bpre, (tau + 1) & 7);
    issue_tile(tau + 3);
    asm volatile("" ::: "memory");
    const float* axs = &Ax[tau & 3][0];
    #pragma unroll
    for (int t = 0; t < 4; ++t) {
      const int rb  = (t * 16 + ln) * 64;
      const int w00 = (kg * 8) ^ sw;
      float4 a0 = *(const float4*)(axs + rb + w00);
      float4 a1 = *(const float4*)(axs + rb + (w00 ^ 4));
      float4 a2 = *(const float4*)(axs + rb + 32 + w00);
      float4 a3 = *(const float4*)(axs + rb + 32 + (w00 ^ 4));
      f16x8 af0 = cvt8(a0, a1);
      f16x8 af1 = cvt8(a2, a3);
      #pragma unroll
      for (int g = 0; g < 4; ++g) {
        acc[t][g] = __builtin_amdgcn_mfma_f32_16x16x32_f16(af0, bcon[g][0], acc[t][g], 0, 0, 0);
        acc[t][g] = __builtin_amdgcn_mfma_f32_16x16x32_f16(af1, bcon[g][1], acc[t][g], 0, 0, 0);
      }
    }
  };

  issue_tile(0); issue_tile(1); issue_tile(2);
  asm volatile("" ::: "memory");
  f16x8 bA[4][2], bB[4][2];
  load_bfr(bA, 0);

  for (int cc = 0; cc < 8; ++cc) {
    #pragma unroll
    for (int t = 0; t < 4; ++t)
      #pragma unroll
      for (int g = 0; g < 4; ++g) acc[t][g] = (f32x4){0.0f, 0.0f, 0.0f, 0.0f};

    #pragma unroll
    for (int kp = 0; kp < 4; ++kp) {
      phaseA_iter(cc * 8 + 2 * kp,     bA, bB);
      phaseA_iter(cc * 8 + 2 * kp + 1, bB, bA);
    }

    #pragma unroll
    for (int s = 0; s < 8; ++s) {
      const int st   = cc * 8 + s;
      const int half = s & 1;
      f16x8 ah0 = (f16x8){0, 0, 0, 0, 0, 0, 0, 0};
      f16x8 ah1 = (f16x8){0, 0, 0, 0, 0, 0, 0, 0};
      if ((ln >> 3) == half) {
        const _Float16* hr = &hbuf[st & 1][ln & 7][0];
        ah0 = *(const f16x8*)(hr + kg * 8);
        ah1 = *(const f16x8*)(hr + kg * 8 + 32);
      }
      f32x4 gf[4];
      #pragma unroll
      for (int g = 0; g < 4; ++g) {
        gf[g] = __builtin_amdgcn_mfma_f32_16x16x32_f16(ah0, whhf[g][0], acc[s >> 1][g], 0, 0, 0);
        gf[g] = __builtin_amdgcn_mfma_f32_16x16x32_f16(ah1, whhf[g][1], gf[g], 0, 0, 0);
      }
      if ((kg >> 1) == half) {
        const int b0 = (kg & 1) * 4;
        #pragma unroll
        for (int r = 0; r < 4; ++r) {
          const float iv = sigm(gf[0][r] + bsum[0]);
          const float fv = sigm(gf[1][r] + bsum[1]);
          const float gv = tanh_f(gf[2][r] + bsum[2]);
          const float ov = sigm(gf[3][r] + bsum[3]);
          const float cn = fv * cb[b0 + r][u] + iv * gv;
          cb[b0 + r][u] = cn;
          const float hn = ov * tanh_f(cn);
          hbuf[(st + 1) & 1][b0 + r][u] = (_Float16)hn;
          if (st == T_SZ - 1) h32[b0 + r][u] = hn;
        }
      }
      asm volatile("s_waitcnt lgkmcnt(0)" ::: "memory");
      __builtin_amdgcn_s_barrier();
    }
  }

  __syncthreads();
  if (tid < 16) {
    const int r = tid >> 1, j = tid & 1;
    float a = bfc[j];
    #pragma unroll
    for (int uu = 0; uu < 64; ++uu) a += h32[r][uu] * Wfc[j * 64 + uu];
    out[(size_t)(br0 + r) * 2 + j] = a;
  }
}

extern "C" void kernel_launch(void* const* d_in, const int* in_sizes, int n_in,
                              void* d_out, int out_size, void* d_ws, size_t ws_size,
                              hipStream_t stream) {
  const float* x   = (const float*)d_in[0];
  const float* Wih = (const float*)d_in[1];
  const float* Whh = (const float*)d_in[2];
  const float* bih = (const float*)d_in[3];
  const float* bhh = (const float*)d_in[4];
  const float* Wfc = (const float*)d_in[5];
  const float* bfc = (const float*)d_in[6];
  float* out = (float*)d_out;
  _Float16* ws = (_Float16*)d_ws;

  transcode_f16<<<dim3(144), dim3(256), 0, stream>>>(Wih, Whh, ws);

  const size_t need = (size_t)(WIH_ELEMS + WHH_ELEMS) * 2 + XG_ELEMS * 2;
  if (ws_size >= need) {
    _Float16* xg = ws + WIH_ELEMS + WHH_ELEMS;
    xg_gemm<<<dim3(B_SZ), dim3(256), 0, stream>>>(x, ws, bih, bhh, xg);
    lstm_scan<<<dim3(B_SZ / 8), dim3(256), 0, stream>>>(xg, ws, Wfc, bfc, out);
  } else {
    lstm_fused_fb<<<dim3(B_SZ / 8), dim3(256), 0, stream>>>(x, ws, bih, bhh, Wfc, bfc, out);
  }
}

// Round 8
// 260.232 us; speedup vs baseline: 2.1231x; 1.3121x over previous
//
#include <hip/hip_runtime.h>

#define B_SZ 4096
#define T_SZ 64
#define F_SZ 512
#define H_SZ 64
#define BR 8                    // 512 blocks = 2 blocks/CU, zero tail
#define WIH_ELEMS (256 * 512)

typedef _Float16 f16x8 __attribute__((ext_vector_type(8)));
typedef float f32x4 __attribute__((ext_vector_type(4)));

__device__ __forceinline__ float fast_rcp(float x) { return __builtin_amdgcn_rcpf(x); }
__device__ __forceinline__ float sigm(float x) { return fast_rcp(1.0f + __expf(-x)); }
__device__ __forceinline__ float tanh_f(float x) {
  x = fminf(15.0f, fmaxf(-15.0f, x));
  float e = __expf(2.0f * x);
  return (e - 1.0f) * fast_rcp(e + 1.0f);
}
__device__ __forceinline__ f16x8 cvt8(float4 a, float4 b) {
  f16x8 h;
  h[0] = (_Float16)a.x; h[1] = (_Float16)a.y; h[2] = (_Float16)a.z; h[3] = (_Float16)a.w;
  h[4] = (_Float16)b.x; h[5] = (_Float16)b.y; h[6] = (_Float16)b.z; h[7] = (_Float16)b.w;
  return h;
}

__global__ void transcode_f16(const float* __restrict__ Wih, const float* __restrict__ Whh,
                              _Float16* __restrict__ ws) {
  const int i4 = (blockIdx.x * 256 + threadIdx.x) * 4;
  if (i4 < WIH_ELEMS) {
    float4 v = *(const float4*)(Wih + i4);
    ws[i4] = (_Float16)v.x; ws[i4+1] = (_Float16)v.y; ws[i4+2] = (_Float16)v.z; ws[i4+3] = (_Float16)v.w;
  } else {
    const int j4 = i4 - WIH_ELEMS;
    float4 v = *(const float4*)(Whh + j4);
    _Float16* w2 = ws + WIH_ELEMS;
    w2[j4] = (_Float16)v.x; w2[j4+1] = (_Float16)v.y; w2[j4+2] = (_Float16)v.z; w2[j4+3] = (_Float16)v.w;
  }
}

// Fused LSTM. Tile = 64 m-rows x 128 k fp32 (32KB, 512B-contiguous per row), 2-slot ring,
// 4 tiles per 8-step chunk. Per iteration the VMEM stream is shaped so that NO wait ever
// targets an HBM load younger than ~1 full iteration:
//   top: vmcnt(0)+barrier   [queue = B(tau,h0)+D(tau) only -> not an over-drain]
//   loadB(h1) -> consume h0 -> loadB(next,h0) -> issueD(tau+1) -> consume h1
// Compiler-tracked B waits (vmcnt(8)/(16)) leave D(tau+1) in flight; D(tau+1) streams
// through consume-h1 + next top-wait + phase B. All loads compiler-tracked (no asm loads).
__global__ __launch_bounds__(256, 2)
void lstm_fused(const float* __restrict__ x, const _Float16* __restrict__ ws,
                const float* __restrict__ bih, const float* __restrict__ bhh,
                const float* __restrict__ Wfc, const float* __restrict__ bfc,
                float* __restrict__ out)
{
  __shared__ __align__(16) float Ax[2][64 * 128];     // 64 KB ring
  __shared__ __align__(16) _Float16 hbuf[2][8][72];
  __shared__ float cb[8][64];
  __shared__ float h32[8][64];

  const int tid  = threadIdx.x;
  const int wv   = tid >> 6;
  const int lane = tid & 63;
  const int ln   = lane & 15;
  const int kg   = lane >> 4;
  const int br0  = blockIdx.x * BR;
  const int u    = wv * 16 + ln;

  const _Float16* Wihh = ws;
  const _Float16* Whhh = ws + WIH_ELEMS;

  for (int i = tid; i < 2 * 8 * 72; i += 256) (&hbuf[0][0][0])[i] = (_Float16)0.0f;
  for (int i = tid; i < 8 * 64; i += 256) (&cb[0][0])[i] = 0.0f;

  // Whh fragments pinned in registers for all 64 steps (plain loads, drained by syncthreads)
  f16x8 whhf[4][2];
  #pragma unroll
  for (int g = 0; g < 4; ++g)
    #pragma unroll
    for (int k2 = 0; k2 < 2; ++k2)
      whhf[g][k2] = *(const f16x8*)(Whhh + (size_t)((g * 4 + wv) * 16 + ln) * H_SZ
                                         + kg * 8 + k2 * 32);
  float bsum[4];
  #pragma unroll
  for (int g = 0; g < 4; ++g) bsum[g] = bih[g * 64 + u] + bhh[g * 64 + u];

  __syncthreads();   // zeros visible; full drain BEFORE the counted stream begins

  // DMA: tile q (0..31) = chunk q>>2, k-quarter q&3. Wave wv stages rows [wv*16, wv*16+16):
  // 8 instrs x 1KB; instr j = rows {wv*16+2j, +1}; lane l -> row +=(l>>5), granule l&31.
  // Source granule XOR'd by (row&7) (both-sides swizzle; LDS dest linear as required).
  auto issueD = [&](int q) {
    const int qa = q < 32 ? q : 31;          // tail dummy: keeps counts uniform, never read
    const int cc = qa >> 2, kq = qa & 3, slot = q & 1;
    #pragma unroll
    for (int j = 0; j < 8; ++j) {
      const int row = wv * 16 + 2 * j + (lane >> 5);
      const int gs  = (lane & 31) ^ (row & 7);
      const float* src = x + (size_t)(br0 + (row & 7)) * (T_SZ * F_SZ)
                           + (size_t)(cc * 8 + (row >> 3)) * F_SZ + kq * 128 + gs * 4;
      __builtin_amdgcn_global_load_lds(src, &Ax[slot][(wv * 16 + 2 * j) * 128], 16, 0, 0);
    }
  };
  // B-fragments for K-half h of k-quarter kq: 8 x 16B loads (L2-hot fp16 Wih)
  auto loadB = [&](f16x8 (&st)[4][2], int kq, int h) {
    #pragma unroll
    for (int g = 0; g < 4; ++g)
      #pragma unroll
      for (int ks = 0; ks < 2; ++ks)
        st[g][ks] = *(const f16x8*)(Wihh + (size_t)((g * 4 + wv) * 16 + ln) * F_SZ
                                         + kq * 128 + h * 64 + ks * 32 + kg * 8);
  };

  f32x4 acc[4][4];
  auto consume = [&](const f16x8 (&st)[4][2], int slot, int h) {
    const float* axs = &Ax[slot][0];
    #pragma unroll
    for (int mt = 0; mt < 4; ++mt) {
      const float* rowp = axs + (size_t)(mt * 16 + ln) * 128;
      #pragma unroll
      for (int ks = 0; ks < 2; ++ks) {
        const int G  = h * 16 + ks * 8 + kg * 2;
        const int p0 = G ^ (ln & 7);
        const int p1 = (G + 1) ^ (ln & 7);
        float4 a0 = *(const float4*)(rowp + p0 * 4);
        float4 a1 = *(const float4*)(rowp + p1 * 4);
        f16x8 af = cvt8(a0, a1);
        #pragma unroll
        for (int g = 0; g < 4; ++g)
          acc[mt][g] = __builtin_amdgcn_mfma_f32_16x16x32_f16(af, st[g][ks], acc[mt][g], 0, 0, 0);
      }
    }
  };

  f16x8 sA[4][2], sB[4][2];
  // Prologue: D(0) + B(0,h0) in flight; iter 0's top wait lands them.
  issueD(0);
  loadB(sA, 0, 0);

  for (int cc = 0; cc < 8; ++cc) {
    #pragma unroll
    for (int mt = 0; mt < 4; ++mt)
      #pragma unroll
      for (int g = 0; g < 4; ++g) acc[mt][g] = (f32x4){0.0f, 0.0f, 0.0f, 0.0f};

    // ---- Phase A: 4 x 128k tiles ----
    #pragma unroll
    for (int kp = 0; kp < 4; ++kp) {
      const int tau = cc * 4 + kp;
      asm volatile("s_waitcnt vmcnt(0)" ::: "memory");   // = wait D(tau); queue holds only it+B
      __builtin_amdgcn_s_barrier();
      __builtin_amdgcn_sched_barrier(0);
      loadB(sB, kp, 1);
      __builtin_amdgcn_sched_barrier(0);
      consume(sA, tau & 1, 0);
      __builtin_amdgcn_sched_barrier(0);
      loadB(sA, (kp + 1) & 3, 0);
      issueD(tau + 1);                                   // into the other slot: safe post-barrier
      __builtin_amdgcn_sched_barrier(0);
      consume(sB, tau & 1, 1);
    }

    // ---- Phase B: 8 sequential steps; step s -> m-tile s>>1, half s&1 ----
    #pragma unroll
    for (int s = 0; s < 8; ++s) {
      const int st   = cc * 8 + s;
      const int half = s & 1;
      f16x8 ah0 = (f16x8){0, 0, 0, 0, 0, 0, 0, 0};
      f16x8 ah1 = (f16x8){0, 0, 0, 0, 0, 0, 0, 0};
      if ((ln >> 3) == half) {
        const _Float16* hr = &hbuf[st & 1][ln & 7][0];
        ah0 = *(const f16x8*)(hr + kg * 8);
        ah1 = *(const f16x8*)(hr + kg * 8 + 32);
      }
      f32x4 gf[4];
      #pragma unroll
      for (int g = 0; g < 4; ++g) {
        gf[g] = __builtin_amdgcn_mfma_f32_16x16x32_f16(ah0, whhf[g][0], acc[s >> 1][g], 0, 0, 0);
        gf[g] = __builtin_amdgcn_mfma_f32_16x16x32_f16(ah1, whhf[g][1], gf[g], 0, 0, 0);
      }
      if ((kg >> 1) == half) {
        const int b0 = (kg & 1) * 4;
        #pragma unroll
        for (int r = 0; r < 4; ++r) {
          const float iv = sigm(gf[0][r] + bsum[0]);
          const float fv = sigm(gf[1][r] + bsum[1]);
          const float gv = tanh_f(gf[2][r] + bsum[2]);
          const float ov = sigm(gf[3][r] + bsum[3]);
          const float cn = fv * cb[b0 + r][u] + iv * gv;
          cb[b0 + r][u] = cn;
          const float hn = ov * tanh_f(cn);
          hbuf[(st + 1) & 1][b0 + r][u] = (_Float16)hn;
          if (st == T_SZ - 1) h32[b0 + r][u] = hn;
        }
      }
      asm volatile("s_waitcnt lgkmcnt(0)" ::: "memory");
      __builtin_amdgcn_s_barrier();                      // raw: D(next chunk) stays in flight
      __builtin_amdgcn_sched_barrier(0);
    }
  }

  __syncthreads();   // epilogue: drains the tail dummy DMA
  if (tid < 16) {
    const int r = tid >> 1, j = tid & 1;
    float a = bfc[j];
    #pragma unroll
    for (int uu = 0; uu < 64; ++uu) a += h32[r][uu] * Wfc[j * 64 + uu];
    out[(size_t)(br0 + r) * 2 + j] = a;
  }
}

extern "C" void kernel_launch(void* const* d_in, const int* in_sizes, int n_in,
                              void* d_out, int out_size, void* d_ws, size_t ws_size,
                              hipStream_t stream) {
  const float* x   = (const float*)d_in[0];
  const float* Wih = (const float*)d_in[1];
  const float* Whh = (const float*)d_in[2];
  const float* bih = (const float*)d_in[3];
  const float* bhh = (const float*)d_in[4];
  const float* Wfc = (const float*)d_in[5];
  const float* bfc = (const float*)d_in[6];
  float* out = (float*)d_out;
  _Float16* ws = (_Float16*)d_ws;   // 288 KB used

  transcode_f16<<<dim3(144), dim3(256), 0, stream>>>(Wih, Whh, ws);
  lstm_fused<<<dim3(B_SZ / BR), dim3(256), 0, stream>>>(x, ws, bih, bhh, Wfc, bfc, out);
}